// Round 1
// baseline (1027.659 us; speedup 1.0000x reference)
//
#include <hip/hip_runtime.h>
#include <math.h>

// Problem constants
#define CC   512          // channels
#define NN   196          // H*W
#define NP   256          // padded N
#define TT   4            // time steps
#define BB   32           // batch
#define TBB  128          // T*B
#define HD   64           // head dim
#define NHH  8            // heads
#define EPS  1e-5f

// strides
#define STEP_T_IN   ((size_t)BB * CC * NN)   // x per-t stride
#define STEP_T_WS   ((size_t)BB * CC * NP)   // ws per-t stride
#define BUF_ELEMS   ((size_t)TBB * CC * NP)  // 16,777,216 floats = 64 MB

// ---------------- K1: head LIF (x -> spike xs, padded layout) ----------------
__global__ __launch_bounds__(256) void k_head_lif(const float* __restrict__ x,
                                                  float* __restrict__ xs) {
    int idx = blockIdx.x * 256 + threadIdx.x;       // (b*C + c) * 256 + np
    int np  = idx & (NP - 1);
    int bc  = idx >> 8;                              // b*512 + c
    size_t bi = (size_t)bc * NN + np;
    size_t bo = (size_t)bc * NP + np;
    if (np >= NN) {
        #pragma unroll
        for (int t = 0; t < TT; ++t) xs[bo + (size_t)t * STEP_T_WS] = 0.f;
        return;
    }
    float v = 0.f;
    #pragma unroll
    for (int t = 0; t < TT; ++t) {
        float xv = x[bi + (size_t)t * STEP_T_IN];
        float h  = v + (xv - v) * 0.5f;              // tau = 2 (exact /2)
        float s  = (h >= 1.0f) ? 1.f : 0.f;
        v        = (h >= 1.0f) ? 0.f : h;            // hard reset, detached
        xs[bo + (size_t)t * STEP_T_WS] = s;
    }
}

// ---------------- K2: conv(1x1)+BN as tiled fp32 GEMM ----------------
// X: [TB, C, NP] ; W: [O=512, C=512] row-major ; Y: [TB, 512, ostride]
// BM=BN=128, BK=16, block=256, 8x8 micro-tile
__global__ __launch_bounds__(256) void k_conv_bn(
    const float* __restrict__ X, const float* __restrict__ W,
    const float* __restrict__ cbp, const float* __restrict__ bgp,
    const float* __restrict__ bbp, const float* __restrict__ bmp,
    const float* __restrict__ bvp, float* __restrict__ Y,
    int ostride, int nlim)
{
    __shared__ float Wt[16][132];   // [k][o] transposed
    __shared__ float Xt[16][132];   // [k][n]
    const int tid = threadIdx.x;
    const int n0  = blockIdx.x * 128;
    const int o0  = blockIdx.y * 128;
    const int tb  = blockIdx.z;
    const float* Xb = X + (size_t)tb * CC * NP;

    const int ow = tid >> 1;               // 0..127 (W-load row)
    const int kq = (tid & 1) * 8;          // 0 or 8
    const int kx = tid >> 4;               // 0..15 (X-load row)
    const int nq = (tid & 15) * 8;         // 0..120
    const int ty = tid >> 4;               // 0..15 (compute o-quad)
    const int tx = tid & 15;               // 0..15 (compute n-quad)

    float acc[8][8];
    #pragma unroll
    for (int i = 0; i < 8; ++i)
        #pragma unroll
        for (int j = 0; j < 8; ++j) acc[i][j] = 0.f;

    for (int c0 = 0; c0 < CC; c0 += 16) {
        float4 w0 = *(const float4*)&W[(size_t)(o0 + ow) * CC + c0 + kq];
        float4 w1 = *(const float4*)&W[(size_t)(o0 + ow) * CC + c0 + kq + 4];
        float4 x0 = *(const float4*)&Xb[(size_t)(c0 + kx) * NP + n0 + nq];
        float4 x1 = *(const float4*)&Xb[(size_t)(c0 + kx) * NP + n0 + nq + 4];
        __syncthreads();
        Wt[kq+0][ow] = w0.x; Wt[kq+1][ow] = w0.y; Wt[kq+2][ow] = w0.z; Wt[kq+3][ow] = w0.w;
        Wt[kq+4][ow] = w1.x; Wt[kq+5][ow] = w1.y; Wt[kq+6][ow] = w1.z; Wt[kq+7][ow] = w1.w;
        *(float4*)&Xt[kx][nq]     = x0;
        *(float4*)&Xt[kx][nq + 4] = x1;
        __syncthreads();
        #pragma unroll
        for (int k = 0; k < 16; ++k) {
            float4 a0 = *(const float4*)&Wt[k][ty*4];
            float4 a1 = *(const float4*)&Wt[k][ty*4 + 64];
            float4 b0 = *(const float4*)&Xt[k][tx*4];
            float4 b1 = *(const float4*)&Xt[k][tx*4 + 64];
            float av[8] = {a0.x,a0.y,a0.z,a0.w,a1.x,a1.y,a1.z,a1.w};
            float bw[8] = {b0.x,b0.y,b0.z,b0.w,b1.x,b1.y,b1.z,b1.w};
            #pragma unroll
            for (int i = 0; i < 8; ++i)
                #pragma unroll
                for (int j = 0; j < 8; ++j)
                    acc[i][j] = fmaf(av[i], bw[j], acc[i][j]);
        }
    }

    #pragma unroll
    for (int ih = 0; ih < 2; ++ih)
    #pragma unroll
    for (int i = 0; i < 4; ++i) {
        int o = o0 + ih*64 + ty*4 + i;
        float inv  = bgp[o] / sqrtf(bvp[o] + EPS);   // reference BN form
        float c1   = cbp[o] - bmp[o];
        float beta = bbp[o];
        float* Yr = Y + ((size_t)tb * CC + o) * (size_t)ostride;
        #pragma unroll
        for (int jh = 0; jh < 2; ++jh) {
            int n = n0 + jh*64 + tx*4;
            float r0 = (acc[ih*4+i][jh*4+0] + c1) * inv + beta;
            float r1 = (acc[ih*4+i][jh*4+1] + c1) * inv + beta;
            float r2 = (acc[ih*4+i][jh*4+2] + c1) * inv + beta;
            float r3 = (acc[ih*4+i][jh*4+3] + c1) * inv + beta;
            if (n + 3 < nlim) {
                *(float4*)&Yr[n] = make_float4(r0, r1, r2, r3);
            } else {
                if (n + 0 < nlim) Yr[n+0] = r0;
                if (n + 1 < nlim) Yr[n+1] = r1;
                if (n + 2 < nlim) Yr[n+2] = r2;
                if (n + 3 < nlim) Yr[n+3] = r3;
            }
        }
    }
}

// ---------------- K3: fused q_on/q_off/push-pull/k/v LIF (in place) ----------------
__global__ __launch_bounds__(256) void k_qkv_lif(
    float* __restrict__ Q, float* __restrict__ K, float* __restrict__ V,
    const float* __restrict__ pushw, const float* __restrict__ pullw,
    const float* __restrict__ ppbp)
{
    int idx = blockIdx.x * 256 + threadIdx.x;
    int np  = idx & (NP - 1);
    int bc  = idx >> 8;
    size_t base = (size_t)bc * NP + np;
    float pw = log1pf(expf(pushw[0]));   // softplus
    float pl = log1pf(expf(pullw[0]));
    float pb = ppbp[0];
    float von = 0.f, voff = 0.f, vpp = 0.f, vk = 0.f, vv = 0.f;
    #pragma unroll
    for (int t = 0; t < TT; ++t) {
        size_t off = base + (size_t)t * STEP_T_WS;
        float qv = Q[off], kv = K[off], xv = V[off];
        float h;
        h = von  + ( qv - von ) * 0.5f; float son  = (h>=1.f)?1.f:0.f; von  = (h>=1.f)?0.f:h;
        h = voff + (-qv - voff) * 0.5f; float soff = (h>=1.f)?1.f:0.f; voff = (h>=1.f)?0.f:h;
        float diff = pw * son - pl * soff + pb;
        h = vpp  + (diff - vpp) * 0.5f; float spp  = (h>=1.f)?1.f:0.f; vpp  = (h>=1.f)?0.f:h;
        h = vk   + ( kv - vk  ) * 0.5f; float sk   = (h>=1.f)?1.f:0.f; vk   = (h>=1.f)?0.f:h;
        h = vv   + ( xv - vv  ) * 0.5f; float sv   = (h>=1.f)?1.f:0.f; vv   = (h>=1.f)?0.f:h;
        Q[off] = spp; K[off] = sk; V[off] = sv;
    }
}

// ---------------- K4: per-(tb,h) attention: kv = K^T V ; O = (Q_pp @ kv) * 0.125 ----------------
__global__ __launch_bounds__(256) void k_attn(
    const float* __restrict__ Qs, const float* __restrict__ Ks,
    const float* __restrict__ Vs, float* __restrict__ O)
{
    __shared__ float A  [64][68];   // phase A: K chunk transposed [n][d]; phase B: Q chunk [d][n]
    __shared__ float Bt [64][68];   // phase A: V chunk transposed [n][e]
    __shared__ float KVs[64][68];   // kv [d][e]
    const int tid = threadIdx.x;
    const int tb  = blockIdx.x >> 3;
    const int h   = blockIdx.x & 7;
    const int ty  = tid >> 4, tx = tid & 15;
    const int ld  = tid >> 2;             // 0..63
    const int lnq = (tid & 3) * 16;       // 0,16,32,48
    const size_t rbase = ((size_t)tb * CC + (size_t)h * HD) * NP;
    const float* Kb = Ks + rbase;
    const float* Vb = Vs + rbase;
    const float* Qb = Qs + rbase;
    float*       Ob = O  + rbase;

    float acc[4][4];
    #pragma unroll
    for (int i = 0; i < 4; ++i)
        #pragma unroll
        for (int j = 0; j < 4; ++j) acc[i][j] = 0.f;

    // ---- phase A: kv[d][e] = sum_{n<196} K[d][n] * V[e][n]
    for (int n0 = 0; n0 < NP; n0 += 64) {
        __syncthreads();
        #pragma unroll
        for (int q4 = 0; q4 < 4; ++q4) {
            int nl = lnq + q4 * 4;
            int n  = n0 + nl;
            float4 k4 = *(const float4*)&Kb[(size_t)ld * NP + n];
            float4 v4 = *(const float4*)&Vb[(size_t)ld * NP + n];
            A [nl+0][ld] = (n+0 < NN) ? k4.x : 0.f;
            A [nl+1][ld] = (n+1 < NN) ? k4.y : 0.f;
            A [nl+2][ld] = (n+2 < NN) ? k4.z : 0.f;
            A [nl+3][ld] = (n+3 < NN) ? k4.w : 0.f;
            Bt[nl+0][ld] = (n+0 < NN) ? v4.x : 0.f;
            Bt[nl+1][ld] = (n+1 < NN) ? v4.y : 0.f;
            Bt[nl+2][ld] = (n+2 < NN) ? v4.z : 0.f;
            Bt[nl+3][ld] = (n+3 < NN) ? v4.w : 0.f;
        }
        __syncthreads();
        #pragma unroll 8
        for (int nl = 0; nl < 64; ++nl) {
            float4 ka = *(const float4*)&A [nl][ty*4];
            float4 vb = *(const float4*)&Bt[nl][tx*4];
            float ks4[4] = {ka.x, ka.y, ka.z, ka.w};
            float vs4[4] = {vb.x, vb.y, vb.z, vb.w};
            #pragma unroll
            for (int i = 0; i < 4; ++i)
                #pragma unroll
                for (int j = 0; j < 4; ++j)
                    acc[i][j] = fmaf(ks4[i], vs4[j], acc[i][j]);
        }
    }
    // stash kv
    #pragma unroll
    for (int i = 0; i < 4; ++i)
        *(float4*)&KVs[ty*4 + i][tx*4] = make_float4(acc[i][0], acc[i][1], acc[i][2], acc[i][3]);

    // ---- phase B: O[e][n] = 0.125 * sum_d kv[d][e] * Q[d][n]
    for (int n0 = 0; n0 < NP; n0 += 64) {
        __syncthreads();   // also covers initial KVs visibility + A reuse
        #pragma unroll
        for (int q4 = 0; q4 < 4; ++q4) {
            int nl = lnq + q4 * 4;
            *(float4*)&A[ld][nl] = *(const float4*)&Qb[(size_t)ld * NP + n0 + nl];
        }
        __syncthreads();
        float accb[4][4];
        #pragma unroll
        for (int i = 0; i < 4; ++i)
            #pragma unroll
            for (int j = 0; j < 4; ++j) accb[i][j] = 0.f;
        #pragma unroll 8
        for (int d = 0; d < 64; ++d) {
            float4 kvv = *(const float4*)&KVs[d][ty*4];
            float4 q4v = *(const float4*)&A  [d][tx*4];
            float kk[4] = {kvv.x, kvv.y, kvv.z, kvv.w};
            float qq[4] = {q4v.x, q4v.y, q4v.z, q4v.w};
            #pragma unroll
            for (int i = 0; i < 4; ++i)
                #pragma unroll
                for (int j = 0; j < 4; ++j)
                    accb[i][j] = fmaf(kk[i], qq[j], accb[i][j]);
        }
        #pragma unroll
        for (int i = 0; i < 4; ++i) {
            *(float4*)&Ob[(size_t)(ty*4 + i) * NP + n0 + tx*4] = make_float4(
                accb[i][0]*0.125f, accb[i][1]*0.125f, accb[i][2]*0.125f, accb[i][3]*0.125f);
        }
    }
}

// ---------------- K5: attn LIF (vth = 0.5), in place ----------------
__global__ __launch_bounds__(256) void k_attn_lif(float* __restrict__ O) {
    int idx = blockIdx.x * 256 + threadIdx.x;
    int np  = idx & (NP - 1);
    int bc  = idx >> 8;
    size_t base = (size_t)bc * NP + np;
    float v = 0.f;
    #pragma unroll
    for (int t = 0; t < TT; ++t) {
        size_t off = base + (size_t)t * STEP_T_WS;
        float xv = O[off];
        float h  = v + (xv - v) * 0.5f;
        float s  = (h >= 0.5f) ? 1.f : 0.f;
        v        = (h >= 0.5f) ? 0.f : h;
        O[off] = s;
    }
}

extern "C" void kernel_launch(void* const* d_in, const int* in_sizes, int n_in,
                              void* d_out, int out_size, void* d_ws, size_t ws_size,
                              hipStream_t stream) {
    const float* x    = (const float*)d_in[0];
    const float* q_cw = (const float*)d_in[1];
    const float* q_cb = (const float*)d_in[2];
    const float* q_bg = (const float*)d_in[3];
    const float* q_bb = (const float*)d_in[4];
    const float* q_bm = (const float*)d_in[5];
    const float* q_bv = (const float*)d_in[6];
    const float* k_cw = (const float*)d_in[7];
    const float* k_cb = (const float*)d_in[8];
    const float* k_bg = (const float*)d_in[9];
    const float* k_bb = (const float*)d_in[10];
    const float* k_bm = (const float*)d_in[11];
    const float* k_bv = (const float*)d_in[12];
    const float* v_cw = (const float*)d_in[13];
    const float* v_cb = (const float*)d_in[14];
    const float* v_bg = (const float*)d_in[15];
    const float* v_bb = (const float*)d_in[16];
    const float* v_bm = (const float*)d_in[17];
    const float* v_bv = (const float*)d_in[18];
    const float* p_cw = (const float*)d_in[19];
    const float* p_cb = (const float*)d_in[20];
    const float* p_bg = (const float*)d_in[21];
    const float* p_bb = (const float*)d_in[22];
    const float* p_bm = (const float*)d_in[23];
    const float* p_bv = (const float*)d_in[24];
    const float* pshw = (const float*)d_in[25];
    const float* pllw = (const float*)d_in[26];
    const float* ppb  = (const float*)d_in[27];
    float* out = (float*)d_out;

    // workspace: 4 x 64MB fp32 buffers (XS reused for attention output O)
    if (ws_size < 4 * BUF_ELEMS * sizeof(float)) return;  // need 256 MB
    float* XS = (float*)d_ws;
    float* Qb = XS + BUF_ELEMS;
    float* Kb = XS + 2 * BUF_ELEMS;
    float* Vb = XS + 3 * BUF_ELEMS;
    float* O  = XS;   // reuse: XS dead after the three projections

    const int elemBlocks = (int)(STEP_T_WS / 256);   // 16384
    dim3 gemmGrid(2, 4, TBB);                        // n-tiles, o-tiles, tb

    k_head_lif<<<elemBlocks, 256, 0, stream>>>(x, XS);
    k_conv_bn<<<gemmGrid, 256, 0, stream>>>(XS, q_cw, q_cb, q_bg, q_bb, q_bm, q_bv, Qb, NP, NP);
    k_conv_bn<<<gemmGrid, 256, 0, stream>>>(XS, k_cw, k_cb, k_bg, k_bb, k_bm, k_bv, Kb, NP, NP);
    k_conv_bn<<<gemmGrid, 256, 0, stream>>>(XS, v_cw, v_cb, v_bg, v_bb, v_bm, v_bv, Vb, NP, NP);
    k_qkv_lif<<<elemBlocks, 256, 0, stream>>>(Qb, Kb, Vb, pshw, pllw, ppb);
    k_attn<<<TBB * NHH, 256, 0, stream>>>(Qb, Kb, Vb, O);
    k_attn_lif<<<elemBlocks, 256, 0, stream>>>(O);
    k_conv_bn<<<gemmGrid, 256, 0, stream>>>(O, p_cw, p_cb, p_bg, p_bb, p_bm, p_bv, out, NN, NN);
}

// Round 2
// 532.385 us; speedup vs baseline: 1.9303x; 1.9303x over previous
//
#include <hip/hip_runtime.h>
#include <hip/hip_bf16.h>
#include <math.h>

typedef unsigned short u16;
typedef unsigned int   u32;

#define CC 512
#define NN 196
#define NP 256
#define TT 4
#define BB 32
#define TBB 128
#define NHH 8
#define HD 64

typedef __attribute__((ext_vector_type(8))) short bf16x8;
typedef __attribute__((ext_vector_type(4))) float f32x4;

#define TSTRIDE   ((size_t)BB * NP * CC)          // 4,194,304 elems per t-slice
#define SPIKE_E   ((size_t)TBB * NP * CC)         // 16,777,216

__device__ __forceinline__ u16 f2bf(float f) {
    __hip_bfloat16 h = __float2bfloat16(f);
    return *(u16*)&h;
}
__device__ __forceinline__ float bf2f(u16 u) {
    u32 ui = ((u32)u) << 16;
    return __uint_as_float(ui);
}
__device__ __forceinline__ u32 pk2(u16 a, u16 b) { return (u32)a | ((u32)b << 16); }

// async 16B/lane global->LDS; lds base must be wave-uniform
__device__ __forceinline__ void gld16(const void* g, void* l) {
    __builtin_amdgcn_global_load_lds(
        (const __attribute__((address_space(1))) void*)g,
        (__attribute__((address_space(3))) void*)l, 16, 0, 0);
}

// ---------------- prep: split fp32 weights into 3 exact bf16 planes ----------------
__global__ __launch_bounds__(256) void k_prep_w(const float* __restrict__ qw, const float* __restrict__ kw,
                                                const float* __restrict__ vw, const float* __restrict__ pw,
                                                u16* __restrict__ W3) {
    size_t idx = (size_t)blockIdx.x * 256 + threadIdx.x;   // 4 * 262144
    int g = (int)(idx >> 18);
    size_t rem = idx & 262143;
    const float* Ws = (g == 0) ? qw : (g == 1) ? kw : (g == 2) ? vw : pw;
    float w  = Ws[rem];
    u16 u0 = f2bf(w);      float b0 = bf2f(u0);
    float r1 = w - b0;
    u16 u1 = f2bf(r1);     float b1 = bf2f(u1);
    float r2 = r1 - b1;
    u16 u2 = f2bf(r2);
    size_t base = (size_t)g * 786432 + rem;
    W3[base] = u0; W3[base + 262144] = u1; W3[base + 524288] = u2;
}

__global__ __launch_bounds__(256) void k_prep_bn(const float* __restrict__ cb, const float* __restrict__ bg,
                                                 const float* __restrict__ bb, const float* __restrict__ bm,
                                                 const float* __restrict__ bv, float* __restrict__ scale,
                                                 float* __restrict__ shift) {
    int o = blockIdx.x * 256 + threadIdx.x;
    if (o >= CC) return;
    float inv = bg[o] / sqrtf(bv[o] + 1e-5f);
    scale[o] = inv;
    shift[o] = (cb[o] - bm[o]) * inv + bb[o];
}

// ---------------- head LIF + transpose: x[t][b][C][196] -> XS[tb][n(256)][C] bf16 spikes ----------------
__global__ __launch_bounds__(256) void k_head_lif(const float* __restrict__ x, u16* __restrict__ XS) {
    __shared__ float T[64][65];
    const int tid = threadIdx.x;
    const int n0 = blockIdx.x * 64;       // 0..3 * 64
    const int b  = blockIdx.y;            // 0..31
    const int ch = blockIdx.z;            // 0..1
    const int n_l = tid & 63;
    const int c_r0 = tid >> 6;            // 0..3
    const int n_r = tid >> 2;             // 0..63
    const int cq  = (tid & 3) * 16;

    for (int cc = 0; cc < 4; ++cc) {
        const int c_base = ch * 256 + cc * 64;
        float v[16];
        #pragma unroll
        for (int j = 0; j < 16; ++j) v[j] = 0.f;
        for (int t = 0; t < TT; ++t) {
            const size_t xb = ((size_t)(t * BB + b) * CC + c_base) * NN;
            float s[16];
            #pragma unroll
            for (int j = 0; j < 16; ++j) {
                int c_l = c_r0 + 4 * j;
                float xv = (n0 + n_l < NN) ? x[xb + (size_t)c_l * NN + n0 + n_l] : 0.f;
                float h = v[j] + (xv - v[j]) * 0.5f;
                s[j] = (h >= 1.f) ? 1.f : 0.f;
                v[j] = (h >= 1.f) ? 0.f : h;
            }
            __syncthreads();
            #pragma unroll
            for (int j = 0; j < 16; ++j) T[c_r0 + 4 * j][n_l] = s[j];
            __syncthreads();
            const size_t ob = (size_t)(t * BB + b) * NP * CC + (size_t)(n0 + n_r) * CC + c_base + cq;
            u16 u[16];
            #pragma unroll
            for (int m = 0; m < 16; ++m) u[m] = (T[cq + m][n_r] != 0.f) ? 0x3F80 : 0;
            uint4 q0 = make_uint4(pk2(u[0],u[1]),  pk2(u[2],u[3]),  pk2(u[4],u[5]),  pk2(u[6],u[7]));
            uint4 q1 = make_uint4(pk2(u[8],u[9]),  pk2(u[10],u[11]),pk2(u[12],u[13]),pk2(u[14],u[15]));
            *(uint4*)(XS + ob)     = q0;
            *(uint4*)(XS + ob + 8) = q1;
            __syncthreads();
        }
    }
}

// ---------------- MFMA GEMM, 3-split bf16 weights ----------------
// QKV=true : D[m=n][n'=o] = spikes(m,k) x W^T(k,o) -> Y fp32 [tb][256][512], BN by col
// QKV=false: D[m=o][n'=n] = W(m,k) x spikes^T(k,n) -> Y fp32 [tb][512][196], BN by row, mask n<196
template<bool QKV>
__global__ __launch_bounds__(256) void k_gemm(const u16* __restrict__ S, const u16* __restrict__ W3,
                                              const float* __restrict__ scale, const float* __restrict__ shift,
                                              float* __restrict__ Y) {
    __shared__ __align__(16) u16 Xt[128 * 32];
    __shared__ __align__(16) u16 Wt[3][128 * 32];
    const int tid  = threadIdx.x;
    const int lane = tid & 63;
    const int w    = tid >> 6;
    const int wtile = blockIdx.x;   // W-row tile (o), 0..3
    const int stile = blockIdx.y;   // spike-row tile (n), 0..1
    const int tb    = blockIdx.z;
    const u16* Sb = S + (size_t)tb * NP * CC + (size_t)(stile * 128) * CC;
    const u16* Wb = W3 + (size_t)(wtile * 128) * CC;

    const int lrow   = lane >> 2;        // 0..15 within 16-row wave chunk
    const int lchunk = (lane & 3) * 8;   // bf16 elems
    const int l15 = lane & 15;
    const int kb  = (lane >> 4) * 8;
    const int wm = (w >> 1) * 64, wn = (w & 1) * 64;
    const int sB = QKV ? wm : wn;        // spike-frag row base
    const int wB = QKV ? wn : wm;        // W-frag row base

    f32x4 acc[4][4];
    f32x4 zz = {0.f, 0.f, 0.f, 0.f};
    #pragma unroll
    for (int i = 0; i < 4; ++i)
        #pragma unroll
        for (int j = 0; j < 4; ++j) acc[i][j] = zz;

    for (int c0 = 0; c0 < CC; c0 += 32) {
        __syncthreads();
        #pragma unroll
        for (int cpy = 0; cpy < 2; ++cpy) {
            int r = w * 32 + cpy * 16 + lrow;
            gld16(Sb + (size_t)r * CC + c0 + lchunk, &Xt[(w * 32 + cpy * 16) * 32]);
        }
        #pragma unroll
        for (int s = 0; s < 3; ++s)
            #pragma unroll
            for (int cpy = 0; cpy < 2; ++cpy) {
                int r = w * 32 + cpy * 16 + lrow;
                gld16(Wb + (size_t)s * CC * CC + (size_t)r * CC + c0 + lchunk,
                      &Wt[s][(w * 32 + cpy * 16) * 32]);
            }
        __syncthreads();

        bf16x8 sf[4];
        #pragma unroll
        for (int i = 0; i < 4; ++i) sf[i] = *(const bf16x8*)&Xt[(sB + i * 16 + l15) * 32 + kb];
        #pragma unroll
        for (int s = 0; s < 3; ++s) {
            bf16x8 wf[4];
            #pragma unroll
            for (int i = 0; i < 4; ++i) wf[i] = *(const bf16x8*)&Wt[s][(wB + i * 16 + l15) * 32 + kb];
            #pragma unroll
            for (int mt = 0; mt < 4; ++mt)
                #pragma unroll
                for (int nt = 0; nt < 4; ++nt) {
                    if (QKV)
                        acc[mt][nt] = __builtin_amdgcn_mfma_f32_16x16x32_bf16(sf[mt], wf[nt], acc[mt][nt], 0, 0, 0);
                    else
                        acc[mt][nt] = __builtin_amdgcn_mfma_f32_16x16x32_bf16(wf[mt], sf[nt], acc[mt][nt], 0, 0, 0);
                }
        }
    }

    // epilogue: C/D layout col = lane&15, row = (lane>>4)*4 + reg
    if (QKV) {
        float* Yb = Y + (size_t)tb * NP * CC;
        #pragma unroll
        for (int nt = 0; nt < 4; ++nt) {
            int o = wtile * 128 + wn + nt * 16 + l15;
            float sc = scale[o], sh = shift[o];
            #pragma unroll
            for (int mt = 0; mt < 4; ++mt) {
                int r0 = stile * 128 + wm + mt * 16 + (lane >> 4) * 4;
                #pragma unroll
                for (int r = 0; r < 4; ++r)
                    Yb[(size_t)(r0 + r) * CC + o] = acc[mt][nt][r] * sc + sh;
            }
        }
    } else {
        float* Yb = Y + (size_t)tb * CC * NN;
        #pragma unroll
        for (int mt = 0; mt < 4; ++mt) {
            int o0 = wtile * 128 + wm + mt * 16 + (lane >> 4) * 4;
            #pragma unroll
            for (int nt = 0; nt < 4; ++nt) {
                int n = stile * 128 + wn + nt * 16 + l15;
                if (n < NN) {
                    #pragma unroll
                    for (int r = 0; r < 4; ++r)
                        Yb[(size_t)(o0 + r) * NN + n] = acc[mt][nt][r] * scale[o0 + r] + shift[o0 + r];
                }
            }
        }
    }
}

// ---------------- fused q_on/q_off/push-pull + k,v LIF, in-place fp32 spikes ----------------
__global__ __launch_bounds__(256) void k_qkv_lif(float* __restrict__ Q, float* __restrict__ K,
                                                 float* __restrict__ V, const float* __restrict__ pw_,
                                                 const float* __restrict__ pl_, const float* __restrict__ pb_) {
    size_t idx = (size_t)blockIdx.x * 256 + threadIdx.x;
    float pw = log1pf(expf(pw_[0]));
    float pl = log1pf(expf(pl_[0]));
    float pb = pb_[0];
    float von = 0.f, voff = 0.f, vpp = 0.f, vk = 0.f, vv = 0.f;
    #pragma unroll
    for (int t = 0; t < TT; ++t) {
        size_t off = idx + (size_t)t * TSTRIDE;
        float qv = Q[off], kv = K[off], xv = V[off];
        float h;
        h = von  + ( qv - von ) * 0.5f; float son  = (h >= 1.f) ? 1.f : 0.f; von  = (h >= 1.f) ? 0.f : h;
        h = voff + (-qv - voff) * 0.5f; float soff = (h >= 1.f) ? 1.f : 0.f; voff = (h >= 1.f) ? 0.f : h;
        float diff = pw * son - pl * soff + pb;
        h = vpp  + (diff - vpp) * 0.5f; float spp  = (h >= 1.f) ? 1.f : 0.f; vpp  = (h >= 1.f) ? 0.f : h;
        h = vk   + ( kv - vk  ) * 0.5f; float sk   = (h >= 1.f) ? 1.f : 0.f; vk   = (h >= 1.f) ? 0.f : h;
        h = vv   + ( xv - vv  ) * 0.5f; float sv   = (h >= 1.f) ? 1.f : 0.f; vv   = (h >= 1.f) ? 0.f : h;
        Q[off] = spp; K[off] = sk; V[off] = sv;
    }
}

// ---------------- attention per (tb,h): kv = K^T V ; O = 0.125 * Q_pp kv -> bf16 [tb][n][C] ----------------
__global__ __launch_bounds__(256) void k_attn(const float* __restrict__ Q, const float* __restrict__ K,
                                              const float* __restrict__ V, u16* __restrict__ OS) {
    __shared__ float Ks[64][68];
    __shared__ float Vs[64][68];
    __shared__ float KVs[64][68];
    const int tid = threadIdx.x;
    const int tb = blockIdx.x >> 3;
    const int h  = blockIdx.x & 7;
    const size_t gb = (size_t)tb * NP * CC + (size_t)h * HD;
    const int lr = tid >> 2;            // 0..63 row
    const int dq = (tid & 3) * 16;
    const int ty = tid >> 4, tx = tid & 15;

    float acc[4][4];
    #pragma unroll
    for (int i = 0; i < 4; ++i)
        #pragma unroll
        for (int j = 0; j < 4; ++j) acc[i][j] = 0.f;

    // phase A: kv[d][e] = sum_{n<196} K[n][d] * V[n][e]
    for (int n0 = 0; n0 < NP; n0 += 64) {
        __syncthreads();
        bool valid = (n0 + lr) < NN;
        const float* kr = K + gb + (size_t)(n0 + lr) * CC + dq;
        const float* vr = V + gb + (size_t)(n0 + lr) * CC + dq;
        #pragma unroll
        for (int i = 0; i < 4; ++i) {
            float4 kk = valid ? *(const float4*)(kr + 4 * i) : make_float4(0, 0, 0, 0);
            float4 vx = valid ? *(const float4*)(vr + 4 * i) : make_float4(0, 0, 0, 0);
            *(float4*)&Ks[lr][dq + 4 * i] = kk;
            *(float4*)&Vs[lr][dq + 4 * i] = vx;
        }
        __syncthreads();
        #pragma unroll 8
        for (int n = 0; n < 64; ++n) {
            float4 ka = *(const float4*)&Ks[n][ty * 4];
            float4 vb = *(const float4*)&Vs[n][tx * 4];
            float a4[4] = {ka.x, ka.y, ka.z, ka.w};
            float b4[4] = {vb.x, vb.y, vb.z, vb.w};
            #pragma unroll
            for (int i = 0; i < 4; ++i)
                #pragma unroll
                for (int j = 0; j < 4; ++j) acc[i][j] = fmaf(a4[i], b4[j], acc[i][j]);
        }
    }
    __syncthreads();
    #pragma unroll
    for (int i = 0; i < 4; ++i)
        *(float4*)&KVs[ty * 4 + i][tx * 4] = make_float4(acc[i][0], acc[i][1], acc[i][2], acc[i][3]);
    __syncthreads();

    // phase B: o[n][e] = 0.125 * sum_d Q[n][d] * kv[d][e]
    for (int n0 = 0; n0 < NP; n0 += 64) {
        const float* qr = Q + gb + (size_t)(n0 + lr) * CC + dq;
        #pragma unroll
        for (int i = 0; i < 4; ++i)
            *(float4*)&Ks[lr][dq + 4 * i] = *(const float4*)(qr + 4 * i);
        __syncthreads();
        float accb[4][4];
        #pragma unroll
        for (int i = 0; i < 4; ++i)
            #pragma unroll
            for (int j = 0; j < 4; ++j) accb[i][j] = 0.f;
        #pragma unroll 8
        for (int d = 0; d < 64; ++d) {
            float qv[4];
            #pragma unroll
            for (int i = 0; i < 4; ++i) qv[i] = Ks[ty * 4 + i][d];
            float4 kvv = *(const float4*)&KVs[d][tx * 4];
            float k4[4] = {kvv.x, kvv.y, kvv.z, kvv.w};
            #pragma unroll
            for (int i = 0; i < 4; ++i)
                #pragma unroll
                for (int j = 0; j < 4; ++j) accb[i][j] = fmaf(qv[i], k4[j], accb[i][j]);
        }
        #pragma unroll
        for (int i = 0; i < 4; ++i) {
            int n = n0 + ty * 4 + i;
            if (n < NN) {
                ushort4 p;
                p.x = f2bf(accb[i][0] * 0.125f);
                p.y = f2bf(accb[i][1] * 0.125f);
                p.z = f2bf(accb[i][2] * 0.125f);
                p.w = f2bf(accb[i][3] * 0.125f);
                *(ushort4*)&OS[(size_t)tb * NP * CC + (size_t)n * CC + (size_t)h * HD + tx * 4] = p;
            }
        }
        __syncthreads();
    }
}

// ---------------- attn LIF (vth=0.5) in-place on bf16 ----------------
__global__ __launch_bounds__(256) void k_attn_lif(u16* __restrict__ OS) {
    size_t idx = (size_t)blockIdx.x * 256 + threadIdx.x;
    float v = 0.f;
    #pragma unroll
    for (int t = 0; t < TT; ++t) {
        size_t off = idx + (size_t)t * TSTRIDE;
        float xv = bf2f(OS[off]);
        float h = v + (xv - v) * 0.5f;
        bool s = (h >= 0.5f);
        v = s ? 0.f : h;
        OS[off] = s ? 0x3F80 : 0;
    }
}

extern "C" void kernel_launch(void* const* d_in, const int* in_sizes, int n_in,
                              void* d_out, int out_size, void* d_ws, size_t ws_size,
                              hipStream_t stream) {
    const float* x    = (const float*)d_in[0];
    const float* q_cw = (const float*)d_in[1];
    const float* q_cb = (const float*)d_in[2];
    const float* q_bg = (const float*)d_in[3];
    const float* q_bb = (const float*)d_in[4];
    const float* q_bm = (const float*)d_in[5];
    const float* q_bv = (const float*)d_in[6];
    const float* k_cw = (const float*)d_in[7];
    const float* k_cb = (const float*)d_in[8];
    const float* k_bg = (const float*)d_in[9];
    const float* k_bb = (const float*)d_in[10];
    const float* k_bm = (const float*)d_in[11];
    const float* k_bv = (const float*)d_in[12];
    const float* v_cw = (const float*)d_in[13];
    const float* v_cb = (const float*)d_in[14];
    const float* v_bg = (const float*)d_in[15];
    const float* v_bb = (const float*)d_in[16];
    const float* v_bm = (const float*)d_in[17];
    const float* v_bv = (const float*)d_in[18];
    const float* p_cw = (const float*)d_in[19];
    const float* p_cb = (const float*)d_in[20];
    const float* p_bg = (const float*)d_in[21];
    const float* p_bb = (const float*)d_in[22];
    const float* p_bm = (const float*)d_in[23];
    const float* p_bv = (const float*)d_in[24];
    const float* pshw = (const float*)d_in[25];
    const float* pllw = (const float*)d_in[26];
    const float* ppb  = (const float*)d_in[27];
    float* out = (float*)d_out;

    // ws map: XS/OS bf16 32MB | Qf 64MB | Kf 64MB | Vf 64MB | W3 6MB | scale/shift 16KB
    if (ws_size < (size_t)242 * 1024 * 1024) return;
    char* W = (char*)d_ws;
    u16*   XS = (u16*)W;
    float* Qf = (float*)(W + ((size_t)32 << 20));
    float* Kf = (float*)(W + ((size_t)96 << 20));
    float* Vf = (float*)(W + ((size_t)160 << 20));
    u16*   W3 = (u16*)(W + ((size_t)224 << 20));
    float* SS = (float*)(W + ((size_t)224 << 20) + 6291456);  // scale[4][512] then shift[4][512]
    float* SH = SS + 2048;

    k_prep_w<<<4096, 256, 0, stream>>>(q_cw, k_cw, v_cw, p_cw, W3);
    k_prep_bn<<<2, 256, 0, stream>>>(q_cb, q_bg, q_bb, q_bm, q_bv, SS + 0,    SH + 0);
    k_prep_bn<<<2, 256, 0, stream>>>(k_cb, k_bg, k_bb, k_bm, k_bv, SS + 512,  SH + 512);
    k_prep_bn<<<2, 256, 0, stream>>>(v_cb, v_bg, v_bb, v_bm, v_bv, SS + 1024, SH + 1024);
    k_prep_bn<<<2, 256, 0, stream>>>(p_cb, p_bg, p_bb, p_bm, p_bv, SS + 1536, SH + 1536);

    k_head_lif<<<dim3(4, 32, 2), 256, 0, stream>>>(x, XS);

    dim3 gg(4, 2, TBB);
    k_gemm<true><<<gg, 256, 0, stream>>>(XS, W3 + 0,         SS + 0,    SH + 0,    Qf);
    k_gemm<true><<<gg, 256, 0, stream>>>(XS, W3 + 786432,    SS + 512,  SH + 512,  Kf);
    k_gemm<true><<<gg, 256, 0, stream>>>(XS, W3 + 2*786432,  SS + 1024, SH + 1024, Vf);

    k_qkv_lif<<<16384, 256, 0, stream>>>(Qf, Kf, Vf, pshw, pllw, ppb);

    k_attn<<<TBB * NHH, 256, 0, stream>>>(Qf, Kf, Vf, XS);   // OS overwrites XS (dead)
    k_attn_lif<<<16384, 256, 0, stream>>>(XS);

    k_gemm<false><<<gg, 256, 0, stream>>>(XS, W3 + 3*786432, SS + 1536, SH + 1536, out);
}

// Round 3
// 494.883 us; speedup vs baseline: 2.0766x; 1.0758x over previous
//
#include <hip/hip_runtime.h>
#include <hip/hip_bf16.h>
#include <math.h>

typedef unsigned short u16;
typedef unsigned int   u32;

#define CC 512
#define NN 196
#define NP 256
#define TT 4
#define BB 32
#define TBB 128
#define NHH 8
#define HD 64

typedef __attribute__((ext_vector_type(8))) short bf16x8;
typedef __attribute__((ext_vector_type(4))) float f32x4;

#define TSTRIDE   ((size_t)BB * NP * CC)          // 4,194,304 elems per t-slice
#define SPIKE_E   ((size_t)TBB * NP * CC)         // 16,777,216

__device__ __forceinline__ u16 f2bf(float f) {
    __hip_bfloat16 h = __float2bfloat16(f);
    return *(u16*)&h;
}
__device__ __forceinline__ float bf2f(u16 u) {
    u32 ui = ((u32)u) << 16;
    return __uint_as_float(ui);
}
__device__ __forceinline__ u32 pk2(u16 a, u16 b) { return (u32)a | ((u32)b << 16); }

// async 16B/lane global->LDS; lds base must be wave-uniform
__device__ __forceinline__ void gld16(const void* g, void* l) {
    __builtin_amdgcn_global_load_lds(
        (const __attribute__((address_space(1))) void*)g,
        (__attribute__((address_space(3))) void*)l, 16, 0, 0);
}

// ---------------- prep: split fp32 weights into 3 exact bf16 planes ----------------
__global__ __launch_bounds__(256) void k_prep_w(const float* __restrict__ qw, const float* __restrict__ kw,
                                                const float* __restrict__ vw, const float* __restrict__ pw,
                                                u16* __restrict__ W3) {
    size_t idx = (size_t)blockIdx.x * 256 + threadIdx.x;   // 4 * 262144
    int g = (int)(idx >> 18);
    size_t rem = idx & 262143;
    const float* Ws = (g == 0) ? qw : (g == 1) ? kw : (g == 2) ? vw : pw;
    float w  = Ws[rem];
    u16 u0 = f2bf(w);      float b0 = bf2f(u0);
    float r1 = w - b0;
    u16 u1 = f2bf(r1);     float b1 = bf2f(u1);
    float r2 = r1 - b1;
    u16 u2 = f2bf(r2);
    size_t base = (size_t)g * 786432 + rem;
    W3[base] = u0; W3[base + 262144] = u1; W3[base + 524288] = u2;
}

__global__ __launch_bounds__(256) void k_prep_bn(const float* __restrict__ cb, const float* __restrict__ bg,
                                                 const float* __restrict__ bb, const float* __restrict__ bm,
                                                 const float* __restrict__ bv, float* __restrict__ scale,
                                                 float* __restrict__ shift) {
    int o = blockIdx.x * 256 + threadIdx.x;
    if (o >= CC) return;
    float inv = bg[o] / sqrtf(bv[o] + 1e-5f);
    scale[o] = inv;
    shift[o] = (cb[o] - bm[o]) * inv + bb[o];
}

// ---------------- head LIF + transpose: x[t][b][C][196] -> XS[tb][n(256)][C] bf16 spikes ----------------
__global__ __launch_bounds__(256) void k_head_lif(const float* __restrict__ x, u16* __restrict__ XS) {
    __shared__ float T[64][65];
    const int tid = threadIdx.x;
    const int n0 = blockIdx.x * 64;       // 0..3 * 64
    const int b  = blockIdx.y;            // 0..31
    const int ch = blockIdx.z;            // 0..1
    const int n_l = tid & 63;
    const int c_r0 = tid >> 6;            // 0..3
    const int n_r = tid >> 2;             // 0..63
    const int cq  = (tid & 3) * 16;

    for (int cc = 0; cc < 4; ++cc) {
        const int c_base = ch * 256 + cc * 64;
        float v[16];
        #pragma unroll
        for (int j = 0; j < 16; ++j) v[j] = 0.f;
        for (int t = 0; t < TT; ++t) {
            const size_t xb = ((size_t)(t * BB + b) * CC + c_base) * NN;
            float s[16];
            #pragma unroll
            for (int j = 0; j < 16; ++j) {
                int c_l = c_r0 + 4 * j;
                float xv = (n0 + n_l < NN) ? x[xb + (size_t)c_l * NN + n0 + n_l] : 0.f;
                float h = v[j] + (xv - v[j]) * 0.5f;
                s[j] = (h >= 1.f) ? 1.f : 0.f;
                v[j] = (h >= 1.f) ? 0.f : h;
            }
            __syncthreads();
            #pragma unroll
            for (int j = 0; j < 16; ++j) T[c_r0 + 4 * j][n_l] = s[j];
            __syncthreads();
            const size_t ob = (size_t)(t * BB + b) * NP * CC + (size_t)(n0 + n_r) * CC + c_base + cq;
            u16 u[16];
            #pragma unroll
            for (int m = 0; m < 16; ++m) u[m] = (T[cq + m][n_r] != 0.f) ? 0x3F80 : 0;
            uint4 q0 = make_uint4(pk2(u[0],u[1]),  pk2(u[2],u[3]),  pk2(u[4],u[5]),  pk2(u[6],u[7]));
            uint4 q1 = make_uint4(pk2(u[8],u[9]),  pk2(u[10],u[11]),pk2(u[12],u[13]),pk2(u[14],u[15]));
            *(uint4*)(XS + ob)     = q0;
            *(uint4*)(XS + ob + 8) = q1;
            __syncthreads();
        }
    }
}

// ---------------- MFMA GEMM, 3-split bf16 weights ----------------
// QKV=true : blockIdx.x = g*4 + wtile (g selects q/k/v); D[m=n][n'=o] -> Y fp32 [tb][256][512]
// QKV=false: D[m=o][n'=n] = W(m,k) x spikes^T(k,n) -> Y fp32 [tb][512][196], mask n<196
template<bool QKV>
__global__ __launch_bounds__(256) void k_gemm(const u16* __restrict__ S, const u16* __restrict__ W3,
                                              const float* __restrict__ scale, const float* __restrict__ shift,
                                              float* __restrict__ Y) {
    __shared__ __align__(16) u16 Xt[128 * 32];
    __shared__ __align__(16) u16 Wt[3][128 * 32];
    const int tid  = threadIdx.x;
    const int lane = tid & 63;
    const int w    = tid >> 6;
    int g, wtile;
    if (QKV) { g = blockIdx.x >> 2; wtile = blockIdx.x & 3; }
    else     { g = 0;               wtile = blockIdx.x;     }
    const int stile = blockIdx.y;   // spike-row tile (n), 0..1
    const int tb    = blockIdx.z;
    const u16* Sb = S + (size_t)tb * NP * CC + (size_t)(stile * 128) * CC;
    const u16* Wb = W3 + (size_t)g * 786432 + (size_t)(wtile * 128) * CC;
    const float* scl = scale + (QKV ? g * 512 : 0);
    const float* shf = shift + (QKV ? g * 512 : 0);
    float* Yg = Y + (QKV ? (size_t)g * 16777216 : 0);

    const int lrow   = lane >> 2;        // 0..15 within 16-row wave chunk
    const int lchunk = (lane & 3) * 8;   // bf16 elems
    const int l15 = lane & 15;
    const int kb  = (lane >> 4) * 8;
    const int wm = (w >> 1) * 64, wn = (w & 1) * 64;
    const int sB = QKV ? wm : wn;        // spike-frag row base
    const int wB = QKV ? wn : wm;        // W-frag row base

    f32x4 acc[4][4];
    f32x4 zz = {0.f, 0.f, 0.f, 0.f};
    #pragma unroll
    for (int i = 0; i < 4; ++i)
        #pragma unroll
        for (int j = 0; j < 4; ++j) acc[i][j] = zz;

    for (int c0 = 0; c0 < CC; c0 += 32) {
        __syncthreads();
        #pragma unroll
        for (int cpy = 0; cpy < 2; ++cpy) {
            int r = w * 32 + cpy * 16 + lrow;
            gld16(Sb + (size_t)r * CC + c0 + lchunk, &Xt[(w * 32 + cpy * 16) * 32]);
        }
        #pragma unroll
        for (int s = 0; s < 3; ++s)
            #pragma unroll
            for (int cpy = 0; cpy < 2; ++cpy) {
                int r = w * 32 + cpy * 16 + lrow;
                gld16(Wb + (size_t)s * CC * CC + (size_t)r * CC + c0 + lchunk,
                      &Wt[s][(w * 32 + cpy * 16) * 32]);
            }
        __syncthreads();

        bf16x8 sf[4];
        #pragma unroll
        for (int i = 0; i < 4; ++i) sf[i] = *(const bf16x8*)&Xt[(sB + i * 16 + l15) * 32 + kb];
        #pragma unroll
        for (int s = 0; s < 3; ++s) {
            bf16x8 wf[4];
            #pragma unroll
            for (int i = 0; i < 4; ++i) wf[i] = *(const bf16x8*)&Wt[s][(wB + i * 16 + l15) * 32 + kb];
            #pragma unroll
            for (int mt = 0; mt < 4; ++mt)
                #pragma unroll
                for (int nt = 0; nt < 4; ++nt) {
                    if (QKV)
                        acc[mt][nt] = __builtin_amdgcn_mfma_f32_16x16x32_bf16(sf[mt], wf[nt], acc[mt][nt], 0, 0, 0);
                    else
                        acc[mt][nt] = __builtin_amdgcn_mfma_f32_16x16x32_bf16(wf[mt], sf[nt], acc[mt][nt], 0, 0, 0);
                }
        }
    }

    // epilogue: C/D layout col = lane&15, row = (lane>>4)*4 + reg
    if (QKV) {
        float* Yb = Yg + (size_t)tb * NP * CC;
        #pragma unroll
        for (int nt = 0; nt < 4; ++nt) {
            int o = wtile * 128 + wn + nt * 16 + l15;
            float sc = scl[o], sh = shf[o];
            #pragma unroll
            for (int mt = 0; mt < 4; ++mt) {
                int r0 = stile * 128 + wm + mt * 16 + (lane >> 4) * 4;
                #pragma unroll
                for (int r = 0; r < 4; ++r)
                    Yb[(size_t)(r0 + r) * CC + o] = acc[mt][nt][r] * sc + sh;
            }
        }
    } else {
        float* Yb = Yg + (size_t)tb * CC * NN;
        #pragma unroll
        for (int mt = 0; mt < 4; ++mt) {
            int o0 = wtile * 128 + wm + mt * 16 + (lane >> 4) * 4;
            #pragma unroll
            for (int nt = 0; nt < 4; ++nt) {
                int n = stile * 128 + wn + nt * 16 + l15;
                if (n < NN) {
                    #pragma unroll
                    for (int r = 0; r < 4; ++r)
                        Yb[(size_t)(o0 + r) * NN + n] = acc[mt][nt][r] * scl[o0 + r] + shf[o0 + r];
                }
            }
        }
    }
}

// ---------------- fused q_on/q_off/push-pull + k,v LIF, in-place fp32 spikes ----------------
__global__ __launch_bounds__(256) void k_qkv_lif(float* __restrict__ Q, float* __restrict__ K,
                                                 float* __restrict__ V, const float* __restrict__ pw_,
                                                 const float* __restrict__ pl_, const float* __restrict__ pb_) {
    size_t idx = (size_t)blockIdx.x * 256 + threadIdx.x;
    float pw = log1pf(expf(pw_[0]));
    float pl = log1pf(expf(pl_[0]));
    float pb = pb_[0];
    float von = 0.f, voff = 0.f, vpp = 0.f, vk = 0.f, vv = 0.f;
    #pragma unroll
    for (int t = 0; t < TT; ++t) {
        size_t off = idx + (size_t)t * TSTRIDE;
        float qv = Q[off], kv = K[off], xv = V[off];
        float h;
        h = von  + ( qv - von ) * 0.5f; float son  = (h >= 1.f) ? 1.f : 0.f; von  = (h >= 1.f) ? 0.f : h;
        h = voff + (-qv - voff) * 0.5f; float soff = (h >= 1.f) ? 1.f : 0.f; voff = (h >= 1.f) ? 0.f : h;
        float diff = pw * son - pl * soff + pb;
        h = vpp  + (diff - vpp) * 0.5f; float spp  = (h >= 1.f) ? 1.f : 0.f; vpp  = (h >= 1.f) ? 0.f : h;
        h = vk   + ( kv - vk  ) * 0.5f; float sk   = (h >= 1.f) ? 1.f : 0.f; vk   = (h >= 1.f) ? 0.f : h;
        h = vv   + ( xv - vv  ) * 0.5f; float sv   = (h >= 1.f) ? 1.f : 0.f; vv   = (h >= 1.f) ? 0.f : h;
        Q[off] = spp; K[off] = sk; V[off] = sv;
    }
}

// ---------------- MFMA attention per (tb,h): kv = K^T V ; O = 0.125 * Q_pp kv -> bf16 [tb][n][C] ----------------
// Inputs are fp32 spike tensors [tb][n(256)][C]; staged to LDS as bf16 (exact: spikes in {0,1}).
// Phase A: Kt/Vt transposed [d][n-chunk 128] (pad 136); 2 chunks over n.
// kv integers <=196, exact in bf16; phase B: A = Q rows [n][d], B^T = kv^T rows [e][d].
__global__ __launch_bounds__(256) void k_attn(const float* __restrict__ Q, const float* __restrict__ K,
                                              const float* __restrict__ V, u16* __restrict__ OS) {
    __shared__ __align__(16) u16 sm[19584];   // max(2*64*136, 208*72 + 64*72) u16 = 39168 B
    u16* Kt  = sm;            // phase A: [64][136]
    u16* Vt  = sm + 8704;     // phase A: [64][136]
    u16* Qs  = sm;            // phase B: [208][72]
    u16* kvT = sm + 14976;    // phase B: [64][72]

    const int tid = threadIdx.x;
    const int tb  = blockIdx.x >> 3;
    const int h   = blockIdx.x & 7;
    const size_t gb = (size_t)tb * (NP * CC) + (size_t)h * HD;

    const int srow = tid >> 2;            // 0..63 staging row
    const int sdq  = (tid & 3) * 16;      // 0,16,32,48

    const int lane = tid & 63;
    const int w    = tid >> 6;
    const int l15  = lane & 15;
    const int kb8  = (lane >> 4) * 8;
    const int quad = (lane >> 4) * 4;
    const int dh = (w >> 1) * 32, eh = (w & 1) * 32;

    f32x4 accA[2][2];
    f32x4 zz = {0.f, 0.f, 0.f, 0.f};
    #pragma unroll
    for (int i = 0; i < 2; ++i)
        #pragma unroll
        for (int j = 0; j < 2; ++j) accA[i][j] = zz;

    // ---- phase A over 2 n-chunks of 128
    #pragma unroll
    for (int ch = 0; ch < 2; ++ch) {
        if (ch) __syncthreads();   // waves done reading previous chunk
        #pragma unroll
        for (int c = 0; c < 2; ++c) {
            int n  = ch * 128 + c * 64 + srow;
            int nl = (c * 64 + srow);                 // column within chunk
            bool valid = n < NN;
            const float* kr = K + gb + (size_t)n * CC + sdq;
            const float* vr = V + gb + (size_t)n * CC + sdq;
            #pragma unroll
            for (int i = 0; i < 4; ++i) {
                float4 kk = valid ? *(const float4*)(kr + 4 * i) : make_float4(0, 0, 0, 0);
                float4 vx = valid ? *(const float4*)(vr + 4 * i) : make_float4(0, 0, 0, 0);
                int d = sdq + 4 * i;
                Kt[(d + 0) * 136 + nl] = (kk.x != 0.f) ? 0x3F80 : 0;
                Kt[(d + 1) * 136 + nl] = (kk.y != 0.f) ? 0x3F80 : 0;
                Kt[(d + 2) * 136 + nl] = (kk.z != 0.f) ? 0x3F80 : 0;
                Kt[(d + 3) * 136 + nl] = (kk.w != 0.f) ? 0x3F80 : 0;
                Vt[(d + 0) * 136 + nl] = (vx.x != 0.f) ? 0x3F80 : 0;
                Vt[(d + 1) * 136 + nl] = (vx.y != 0.f) ? 0x3F80 : 0;
                Vt[(d + 2) * 136 + nl] = (vx.z != 0.f) ? 0x3F80 : 0;
                Vt[(d + 3) * 136 + nl] = (vx.w != 0.f) ? 0x3F80 : 0;
            }
        }
        __syncthreads();
        #pragma unroll
        for (int k0 = 0; k0 < 128; k0 += 32) {
            bf16x8 af[2], bv[2];
            #pragma unroll
            for (int i = 0; i < 2; ++i) {
                af[i] = *(const bf16x8*)&Kt[(dh + i * 16 + l15) * 136 + k0 + kb8];
                bv[i] = *(const bf16x8*)&Vt[(eh + i * 16 + l15) * 136 + k0 + kb8];
            }
            #pragma unroll
            for (int i = 0; i < 2; ++i)
                #pragma unroll
                for (int j = 0; j < 2; ++j)
                    accA[i][j] = __builtin_amdgcn_mfma_f32_16x16x32_bf16(af[i], bv[j], accA[i][j], 0, 0, 0);
        }
    }
    __syncthreads();   // all waves done with Kt/Vt before overwrite

    // ---- write kv^T (bf16, exact: integers <= 196) and stage Q
    #pragma unroll
    for (int i = 0; i < 2; ++i)
        #pragma unroll
        for (int j = 0; j < 2; ++j)
            #pragma unroll
            for (int r = 0; r < 4; ++r) {
                int e = eh + j * 16 + l15;
                int d = dh + i * 16 + quad + r;
                kvT[e * 72 + d] = f2bf(accA[i][j][r]);
            }
    #pragma unroll
    for (int p = 0; p < 4; ++p) {
        int n = p * 64 + srow;
        if (n < 208) {
            const float* qr = Q + gb + (size_t)n * CC + sdq;
            #pragma unroll
            for (int i = 0; i < 4; ++i) {
                float4 qq = *(const float4*)(qr + 4 * i);
                int d = sdq + 4 * i;
                Qs[n * 72 + d + 0] = (qq.x != 0.f) ? 0x3F80 : 0;
                Qs[n * 72 + d + 1] = (qq.y != 0.f) ? 0x3F80 : 0;
                Qs[n * 72 + d + 2] = (qq.z != 0.f) ? 0x3F80 : 0;
                Qs[n * 72 + d + 3] = (qq.w != 0.f) ? 0x3F80 : 0;
            }
        }
    }
    __syncthreads();

    // ---- phase B: wave w owns e-tile [w*16, w*16+16)
    bf16x8 bq0 = *(const bf16x8*)&kvT[(w * 16 + l15) * 72 + 0  + kb8];
    bf16x8 bq1 = *(const bf16x8*)&kvT[(w * 16 + l15) * 72 + 32 + kb8];
    u16* ob = OS + (size_t)tb * (NP * CC) + (size_t)h * HD + w * 16 + l15;
    #pragma unroll
    for (int nt = 0; nt < 13; ++nt) {
        f32x4 acc = zz;
        bf16x8 a0 = *(const bf16x8*)&Qs[(nt * 16 + l15) * 72 + 0  + kb8];
        bf16x8 a1 = *(const bf16x8*)&Qs[(nt * 16 + l15) * 72 + 32 + kb8];
        acc = __builtin_amdgcn_mfma_f32_16x16x32_bf16(a0, bq0, acc, 0, 0, 0);
        acc = __builtin_amdgcn_mfma_f32_16x16x32_bf16(a1, bq1, acc, 0, 0, 0);
        #pragma unroll
        for (int r = 0; r < 4; ++r) {
            int n = nt * 16 + quad + r;
            if (n < NN) ob[(size_t)n * CC] = f2bf(acc[r] * 0.125f);
        }
    }
}

// ---------------- attn LIF (vth=0.5) in-place on bf16 ----------------
__global__ __launch_bounds__(256) void k_attn_lif(u16* __restrict__ OS) {
    size_t idx = (size_t)blockIdx.x * 256 + threadIdx.x;
    float v = 0.f;
    #pragma unroll
    for (int t = 0; t < TT; ++t) {
        size_t off = idx + (size_t)t * TSTRIDE;
        float xv = bf2f(OS[off]);
        float h = v + (xv - v) * 0.5f;
        bool s = (h >= 0.5f);
        v = s ? 0.f : h;
        OS[off] = s ? 0x3F80 : 0;
    }
}

extern "C" void kernel_launch(void* const* d_in, const int* in_sizes, int n_in,
                              void* d_out, int out_size, void* d_ws, size_t ws_size,
                              hipStream_t stream) {
    const float* x    = (const float*)d_in[0];
    const float* q_cw = (const float*)d_in[1];
    const float* q_cb = (const float*)d_in[2];
    const float* q_bg = (const float*)d_in[3];
    const float* q_bb = (const float*)d_in[4];
    const float* q_bm = (const float*)d_in[5];
    const float* q_bv = (const float*)d_in[6];
    const float* k_cw = (const float*)d_in[7];
    const float* k_cb = (const float*)d_in[8];
    const float* k_bg = (const float*)d_in[9];
    const float* k_bb = (const float*)d_in[10];
    const float* k_bm = (const float*)d_in[11];
    const float* k_bv = (const float*)d_in[12];
    const float* v_cw = (const float*)d_in[13];
    const float* v_cb = (const float*)d_in[14];
    const float* v_bg = (const float*)d_in[15];
    const float* v_bb = (const float*)d_in[16];
    const float* v_bm = (const float*)d_in[17];
    const float* v_bv = (const float*)d_in[18];
    const float* p_cw = (const float*)d_in[19];
    const float* p_cb = (const float*)d_in[20];
    const float* p_bg = (const float*)d_in[21];
    const float* p_bb = (const float*)d_in[22];
    const float* p_bm = (const float*)d_in[23];
    const float* p_bv = (const float*)d_in[24];
    const float* pshw = (const float*)d_in[25];
    const float* pllw = (const float*)d_in[26];
    const float* ppb  = (const float*)d_in[27];
    float* out = (float*)d_out;

    // ws map: XS/OS bf16 32MB | Qf 64MB | Kf 64MB | Vf 64MB | W3 6MB | scale/shift 16KB
    if (ws_size < (size_t)242 * 1024 * 1024) return;
    char* W = (char*)d_ws;
    u16*   XS = (u16*)W;
    float* Qf = (float*)(W + ((size_t)32 << 20));
    float* Kf = (float*)(W + ((size_t)96 << 20));
    float* Vf = (float*)(W + ((size_t)160 << 20));
    u16*   W3 = (u16*)(W + ((size_t)224 << 20));
    float* SS = (float*)(W + ((size_t)224 << 20) + 6291456);  // scale[4][512] then shift[4][512]
    float* SH = SS + 2048;

    k_prep_w<<<4096, 256, 0, stream>>>(q_cw, k_cw, v_cw, p_cw, W3);
    k_prep_bn<<<2, 256, 0, stream>>>(q_cb, q_bg, q_bb, q_bm, q_bv, SS + 0,    SH + 0);
    k_prep_bn<<<2, 256, 0, stream>>>(k_cb, k_bg, k_bb, k_bm, k_bv, SS + 512,  SH + 512);
    k_prep_bn<<<2, 256, 0, stream>>>(v_cb, v_bg, v_bb, v_bm, v_bv, SS + 1024, SH + 1024);
    k_prep_bn<<<2, 256, 0, stream>>>(p_cb, p_bg, p_bb, p_bm, p_bv, SS + 1536, SH + 1536);

    k_head_lif<<<dim3(4, 32, 2), 256, 0, stream>>>(x, XS);

    // merged Q/K/V projection: blockIdx.x = g*4 + wtile; Y offsets g*64MB (Qf,Kf,Vf contiguous)
    k_gemm<true><<<dim3(12, 2, TBB), 256, 0, stream>>>(XS, W3, SS, SH, Qf);

    k_qkv_lif<<<16384, 256, 0, stream>>>(Qf, Kf, Vf, pshw, pllw, ppb);

    k_attn<<<TBB * NHH, 256, 0, stream>>>(Qf, Kf, Vf, XS);   // OS overwrites XS (dead)
    k_attn_lif<<<16384, 256, 0, stream>>>(XS);

    k_gemm<false><<<dim3(4, 2, TBB), 256, 0, stream>>>(XS, W3 + 3 * 786432, SS + 1536, SH + 1536, out);
}